// Round 3
// baseline (892.474 us; speedup 1.0000x reference)
//
#include <hip/hip_runtime.h>

#define LEAKY 0.01f
#define BN_EPS 1e-5f

// ---------------- degree count ----------------
__global__ __launch_bounds__(256) void k_count(const int* __restrict__ dst,
                                               int* __restrict__ cnt, int e) {
  int i = blockIdx.x * 256 + threadIdx.x;
  if (i < e) atomicAdd(&cnt[dst[i]], 1);
}

// ---------------- exclusive scan A (fused dinv) ----------------
__global__ __launch_bounds__(256) void k_scanA(const int* __restrict__ in,
                                               int* __restrict__ out,
                                               int* __restrict__ bsums,
                                               float* __restrict__ dinv, int n) {
  __shared__ int sdata[256];
  int t = threadIdx.x;
  int base = blockIdx.x * 1024 + t * 4;
  int v[4];
#pragma unroll
  for (int j = 0; j < 4; j++) v[j] = (base + j < n) ? in[base + j] : 0;
#pragma unroll
  for (int j = 0; j < 4; j++)
    if (base + j < n) dinv[base + j] = rsqrtf((float)(v[j] + 1));  // +1 self-loop
  int tsum = v[0] + v[1] + v[2] + v[3];
  sdata[t] = tsum;
  __syncthreads();
  for (int off = 1; off < 256; off <<= 1) {
    int x = (t >= off) ? sdata[t - off] : 0;
    __syncthreads();
    sdata[t] += x;
    __syncthreads();
  }
  int run = sdata[t] - tsum;
#pragma unroll
  for (int j = 0; j < 4; j++) {
    if (base + j < n) out[base + j] = run;
    run += v[j];
  }
  if (t == 255) bsums[blockIdx.x] = sdata[255];
}

__global__ __launch_bounds__(256) void k_scanB(int* __restrict__ bsums, int nb) {
  __shared__ int sdata[256];
  int t = threadIdx.x;
  int v = (t < nb) ? bsums[t] : 0;
  sdata[t] = v;
  __syncthreads();
  for (int off = 1; off < 256; off <<= 1) {
    int x = (t >= off) ? sdata[t - off] : 0;
    __syncthreads();
    sdata[t] += x;
    __syncthreads();
  }
  if (t < nb) bsums[t] = sdata[t] - v;  // exclusive
}

// ---------------- CSR scatter (consumes counts down to 0; bsums fused) ----------------
__global__ __launch_bounds__(256) void k_scatter(const int* __restrict__ src,
                                                 const int* __restrict__ dst,
                                                 const int* __restrict__ off,
                                                 const int* __restrict__ bsums,
                                                 int* __restrict__ cnt,
                                                 int* __restrict__ csr, int e) {
  int i = blockIdx.x * 256 + threadIdx.x;
  if (i < e) {
    int d = dst[i];
    int p = off[d] + bsums[d >> 10] + (atomicSub(&cnt[d], 1) - 1);
    csr[p] = src[i];
  }
}

// ---------------- 64x64 GEMM: Y[n,64] = X[n,64] @ W ; BN+LeakyReLU fused on X
template <bool BN>
__global__ __launch_bounds__(256) void k_gemm(const float* __restrict__ X,
                                              const float* __restrict__ W,
                                              float* __restrict__ Y, int n,
                                              const double* __restrict__ st,
                                              const float* __restrict__ gamma,
                                              const float* __restrict__ beta) {
  __shared__ float Ws[64][68];
  __shared__ float Xs[64][65];
  __shared__ float smu[64], sisd[64];
  int t = threadIdx.x;
  if (BN) {
    if (t < 64) {
      double mu = st[t] / n;
      double var = st[64 + t] / n - mu * mu;
      smu[t] = (float)mu;
      sisd[t] = (float)(1.0 / sqrt(var + (double)BN_EPS));
    }
    __syncthreads();
  }
  for (int j = t; j < 4096; j += 256) Ws[j >> 6][j & 63] = W[j];
  int rowbase = blockIdx.x * 64;
  for (int j = t; j < 4096; j += 256) {
    int r = j >> 6, c = j & 63;
    int gr = rowbase + r;
    float v = (gr < n) ? X[(size_t)gr * 64 + c] : 0.f;
    if (BN) {
      v = gamma[c] * (v - smu[c]) * sisd[c] + beta[c];
      v = (v >= 0.f) ? v : LEAKY * v;
    }
    Xs[r][c] = v;
  }
  __syncthreads();
  int r = t >> 2;
  int cq = t & 3;
  float acc[16];
#pragma unroll
  for (int j = 0; j < 16; j++) acc[j] = 0.f;
#pragma unroll 4
  for (int k = 0; k < 64; k++) {
    float xv = Xs[r][k];
#pragma unroll
    for (int j = 0; j < 16; j++) acc[j] += xv * Ws[k][cq * 16 + j];
  }
  int gr = rowbase + r;
  if (gr < n) {
#pragma unroll
    for (int j = 0; j < 16; j++) Y[(size_t)gr * 64 + cq * 16 + j] = acc[j];
  }
}

// ---------------- gather aggregation: branch-free 8-deep ILP ----------------
// csr is padded with 8 zero entries past e, so ALL loads are unconditional
// (over-reads hit valid node indices); only the weight is predicated (cndmask).
template <bool STATS>
__global__ __launch_bounds__(256) void k_agg(const float* __restrict__ H,
                                             float* __restrict__ O,
                                             const int* __restrict__ off,
                                             const int* __restrict__ bsums,
                                             const int* __restrict__ csr,
                                             const float* __restrict__ dinv,
                                             const float* __restrict__ bias,
                                             double* __restrict__ st, int n, int e) {
  __shared__ double ls[4][64], lss[4][64];
  int wave = (blockIdx.x * 256 + threadIdx.x) >> 6;
  int lane = threadIdx.x & 63;
  int i = wave;
  float v = 0.f;
  if (i < n) {
    float di = dinv[i];
    int s0 = off[i] + bsums[i >> 10];
    int s1 = (i + 1 < n) ? (off[i + 1] + bsums[(i + 1) >> 10]) : e;
    float acc = H[(size_t)i * 64 + lane] * (di * di);
    for (int j = s0; j < s1; j += 8) {
      int idx[8];
      float w[8], hv[8];
#pragma unroll
      for (int k = 0; k < 8; k++) idx[k] = csr[j + k];  // unconditional, padded
#pragma unroll
      for (int k = 0; k < 8; k++) hv[k] = H[(size_t)idx[k] * 64 + lane];
#pragma unroll
      for (int k = 0; k < 8; k++) w[k] = (j + k < s1) ? di * dinv[idx[k]] : 0.f;
#pragma unroll
      for (int k = 0; k < 8; k++) acc += hv[k] * w[k];
    }
    v = acc + bias[lane];
    O[(size_t)i * 64 + lane] = v;
  }
  if (STATS) {
    int w_ = threadIdx.x >> 6;
    ls[w_][lane] = (double)v;
    lss[w_][lane] = (double)v * (double)v;
    __syncthreads();
    if (w_ == 0) {
      double a = ls[0][lane] + ls[1][lane] + ls[2][lane] + ls[3][lane];
      double b = lss[0][lane] + lss[1][lane] + lss[2][lane] + lss[3][lane];
      atomicAdd(&st[lane], a);
      atomicAdd(&st[64 + lane], b);
    }
  }
}

extern "C" void kernel_launch(void* const* d_in, const int* in_sizes, int n_in,
                              void* d_out, int out_size, void* d_ws, size_t ws_size,
                              hipStream_t stream) {
  const float* x     = (const float*)d_in[0];
  const int*   ei    = (const int*)d_in[1];
  const float* W1    = (const float*)d_in[2];
  const float* b1    = (const float*)d_in[3];
  const float* gamma = (const float*)d_in[4];
  const float* beta  = (const float*)d_in[5];
  const float* W2    = (const float*)d_in[6];
  const float* b2    = (const float*)d_in[7];
  float* out = (float*)d_out;

  int n = in_sizes[0] / 64;
  int e = in_sizes[1] / 2;
  const int* srcv = ei;
  const int* dstv = ei + e;

  char* ws = (char*)d_ws;
  size_t p = 0;
  auto alloc = [&](size_t bytes) {
    void* r = ws + p;
    p += (bytes + 255) & ~(size_t)255;
    return r;
  };
  int*    counts = (int*)alloc((size_t)n * 4);
  int*    off    = (int*)alloc((size_t)n * 4);
  int*    bsums  = (int*)alloc(1024);
  float*  dinv   = (float*)alloc((size_t)n * 4);
  int*    csr    = (int*)alloc((size_t)(e + 8) * 4);  // +8 pad for branch-free loads
  double* st     = (double*)alloc(128 * 8);
  float*  A      = (float*)alloc((size_t)n * 64 * 4);
  float*  B      = (float*)alloc((size_t)n * 64 * 4);

  hipMemsetAsync(counts, 0, (size_t)n * 4, stream);
  hipMemsetAsync(csr + e, 0, 32, stream);  // pad -> valid index 0
  hipMemsetAsync(st, 0, 128 * 8, stream);

  int gE = (e + 255) / 256;
  int nb = (n + 1023) / 1024;
  int gG = (n + 63) / 64;
  int gAgg = (n + 3) / 4;

  k_count<<<gE, 256, 0, stream>>>(dstv, counts, e);
  k_scanA<<<nb, 256, 0, stream>>>(counts, off, bsums, dinv, n);
  k_scanB<<<1, 256, 0, stream>>>(bsums, nb);
  k_scatter<<<gE, 256, 0, stream>>>(srcv, dstv, off, bsums, counts, csr, e);

  k_gemm<false><<<gG, 256, 0, stream>>>(x, W1, A, n, nullptr, nullptr, nullptr);
  k_agg<true><<<gAgg, 256, 0, stream>>>(A, B, off, bsums, csr, dinv, b1, st, n, e);
  k_gemm<true><<<gG, 256, 0, stream>>>(B, W2, A, n, st, gamma, beta);
  k_agg<false><<<gAgg, 256, 0, stream>>>(A, out, off, bsums, csr, dinv, b2, nullptr, n, e);
}

// Round 4
// 849.083 us; speedup vs baseline: 1.0511x; 1.0511x over previous
//
#include <hip/hip_runtime.h>

#define LEAKY 0.01f
#define BN_EPS 1e-5f

// ---------------- degree count ----------------
__global__ __launch_bounds__(256) void k_count(const int* __restrict__ dst,
                                               int* __restrict__ cnt, int e) {
  int i = blockIdx.x * 256 + threadIdx.x;
  if (i < e) atomicAdd(&cnt[dst[i]], 1);
}

// ---------------- scanA: dinv + local exclusive scan of PADDED counts ----------------
// pc[i] = (cnt[i]+3)&~3 ; out[0..n] local-exclusive scan (out[n] = total-at-n position)
__global__ __launch_bounds__(256) void k_scanA(const int* __restrict__ cnt,
                                               int* __restrict__ out,
                                               int* __restrict__ bsums,
                                               float* __restrict__ dinv, int n) {
  __shared__ int sdata[256];
  int t = threadIdx.x;
  int base = blockIdx.x * 1024 + t * 4;
  int pv[4];
#pragma unroll
  for (int j = 0; j < 4; j++) {
    int c = (base + j < n) ? cnt[base + j] : 0;
    if (base + j < n) dinv[base + j] = rsqrtf((float)(c + 1));  // +1 self-loop
    pv[j] = (base + j < n) ? ((c + 3) & ~3) : 0;
  }
  int tsum = pv[0] + pv[1] + pv[2] + pv[3];
  sdata[t] = tsum;
  __syncthreads();
  for (int off = 1; off < 256; off <<= 1) {
    int x = (t >= off) ? sdata[t - off] : 0;
    __syncthreads();
    sdata[t] += x;
    __syncthreads();
  }
  int run = sdata[t] - tsum;  // exclusive prefix of this thread
#pragma unroll
  for (int j = 0; j < 4; j++) {
    if (base + j < n) out[base + j] = run;
    else if (base + j == n) out[n] = run;  // one-past-end slot
    run += pv[j];
  }
  if (t == 255) bsums[blockIdx.x] = sdata[255];
}

__global__ __launch_bounds__(256) void k_scanB(int* __restrict__ bsums, int nb) {
  __shared__ int sdata[256];
  int t = threadIdx.x;
  int v = (t < nb) ? bsums[t] : 0;
  sdata[t] = v;
  __syncthreads();
  for (int off = 1; off < 256; off <<= 1) {
    int x = (t >= off) ? sdata[t - off] : 0;
    __syncthreads();
    sdata[t] += x;
    __syncthreads();
  }
  if (t < nb) bsums[t] = sdata[t] - v;  // exclusive
}

// ---------------- fill pad slots with sentinel n (before scatter consumes cnt) ----------------
__global__ __launch_bounds__(256) void k_padfill(const int* __restrict__ cnt,
                                                 const int* __restrict__ off,
                                                 const int* __restrict__ bsums,
                                                 int* __restrict__ csr,
                                                 float* __restrict__ dinv, int n) {
  int i = blockIdx.x * 256 + threadIdx.x;
  if (i == 0) dinv[n] = 0.f;  // sentinel weight
  if (i < n) {
    int c = cnt[i];
    int pc = (c + 3) & ~3;
    int base = off[i] + bsums[i >> 10];
    for (int j = c; j < pc; j++) csr[base + j] = n;
  }
}

// ---------------- CSR scatter (consumes counts down to 0) ----------------
__global__ __launch_bounds__(256) void k_scatter(const int* __restrict__ src,
                                                 const int* __restrict__ dst,
                                                 const int* __restrict__ off,
                                                 const int* __restrict__ bsums,
                                                 int* __restrict__ cnt,
                                                 int* __restrict__ csr, int e) {
  int i = blockIdx.x * 256 + threadIdx.x;
  if (i < e) {
    int d = dst[i];
    int p = off[d] + bsums[d >> 10] + (atomicSub(&cnt[d], 1) - 1);
    csr[p] = src[i];
  }
}

// ---------------- 64x64 GEMM: Y[n,64] = X[n,64] @ W ; BN+LeakyReLU fused on X
template <bool BN>
__global__ __launch_bounds__(256) void k_gemm(const float* __restrict__ X,
                                              const float* __restrict__ W,
                                              float* __restrict__ Y, int n,
                                              const double* __restrict__ st,
                                              const float* __restrict__ gamma,
                                              const float* __restrict__ beta) {
  __shared__ float Ws[64][68];  // 68: rows 16B-aligned, 2-way-max bank alias
  __shared__ float Xs[64][68];
  __shared__ float smu[64], sisd[64];
  int t = threadIdx.x;
  if (BN) {
    if (t < 64) {
      double mu = st[t] / n;
      double var = st[64 + t] / n - mu * mu;
      smu[t] = (float)mu;
      sisd[t] = (float)(1.0 / sqrt(var + (double)BN_EPS));
    }
    __syncthreads();
  }
  int rowbase = blockIdx.x * 64;
#pragma unroll
  for (int p = 0; p < 4; p++) {
    int idx = (p * 256 + t) * 4;
    int r = idx >> 6, c = idx & 63;
    float4 wv = *(const float4*)&W[idx];
    *(float4*)&Ws[r][c] = wv;
    int gr = rowbase + r;
    float4 v = (gr < n) ? *(const float4*)&X[(size_t)gr * 64 + c]
                        : make_float4(0.f, 0.f, 0.f, 0.f);
    if (BN) {
      float* vp = (float*)&v;
#pragma unroll
      for (int q = 0; q < 4; q++) {
        float z = gamma[c + q] * (vp[q] - smu[c + q]) * sisd[c + q] + beta[c + q];
        vp[q] = (z >= 0.f) ? z : LEAKY * z;
      }
    }
    *(float4*)&Xs[r][c] = v;
  }
  __syncthreads();
  int r = t >> 2;
  int cq = t & 3;
  float acc[16];
#pragma unroll
  for (int j = 0; j < 16; j++) acc[j] = 0.f;
#pragma unroll 4
  for (int k = 0; k < 64; k++) {
    float xv = Xs[r][k];
#pragma unroll
    for (int j = 0; j < 16; j++) acc[j] += xv * Ws[k][cq * 16 + j];
  }
  int gr = rowbase + r;
  if (gr < n) {
#pragma unroll
    for (int q = 0; q < 4; q++)
      *(float4*)&Y[(size_t)gr * 64 + cq * 16 + q * 4] = *(float4*)&acc[q * 4];
  }
}

// ---------------- gather aggregation: 4-deep, named scalars, int4 csr + prefetch ----------------
// Segments padded to x4 with sentinel n; H row n is zeros, dinv[n]=0.
template <bool STATS>
__global__ __launch_bounds__(256) void k_agg(const float* __restrict__ H,
                                             float* __restrict__ O,
                                             const int* __restrict__ off,
                                             const int* __restrict__ bsums,
                                             const int* __restrict__ csr,
                                             const float* __restrict__ dinv,
                                             const float* __restrict__ bias,
                                             double* __restrict__ st, int n) {
  int wave = (blockIdx.x * 256 + threadIdx.x) >> 6;
  int lane = threadIdx.x & 63;
  int i = wave;
  float v = 0.f;
  if (i < n) {
    float di = dinv[i];
    int s0 = off[i] + bsums[i >> 10];
    int s1 = off[i + 1] + bsums[(i + 1) >> 10];
    float acc = H[(size_t)i * 64 + lane] * (di * di);
    const int4* cp = (const int4*)csr;
    int j = s0 >> 2, jend = s1 >> 2;
    int4 q = cp[j];  // safe even if empty (alloc padded); values unused then
    for (; j < jend; ++j) {
      int4 qn = cp[j + 1];  // prefetch next chunk (alloc has tail pad)
      float h0 = H[(size_t)q.x * 64 + lane];
      float h1 = H[(size_t)q.y * 64 + lane];
      float h2 = H[(size_t)q.z * 64 + lane];
      float h3 = H[(size_t)q.w * 64 + lane];
      float w0 = di * dinv[q.x];
      float w1 = di * dinv[q.y];
      float w2 = di * dinv[q.z];
      float w3 = di * dinv[q.w];
      acc += h0 * w0;
      acc += h1 * w1;
      acc += h2 * w2;
      acc += h3 * w3;
      q = qn;
    }
    v = acc + bias[lane];
    O[(size_t)i * 64 + lane] = v;
  }
  if constexpr (STATS) {
    __shared__ double ls[4][64], lss[4][64];
    int w_ = threadIdx.x >> 6;
    ls[w_][lane] = (double)v;
    lss[w_][lane] = (double)v * (double)v;
    __syncthreads();
    if (w_ == 0) {
      double a = ls[0][lane] + ls[1][lane] + ls[2][lane] + ls[3][lane];
      double b = lss[0][lane] + lss[1][lane] + lss[2][lane] + lss[3][lane];
      atomicAdd(&st[lane], a);
      atomicAdd(&st[64 + lane], b);
    }
  }
}

extern "C" void kernel_launch(void* const* d_in, const int* in_sizes, int n_in,
                              void* d_out, int out_size, void* d_ws, size_t ws_size,
                              hipStream_t stream) {
  const float* x     = (const float*)d_in[0];
  const int*   ei    = (const int*)d_in[1];
  const float* W1    = (const float*)d_in[2];
  const float* b1    = (const float*)d_in[3];
  const float* gamma = (const float*)d_in[4];
  const float* beta  = (const float*)d_in[5];
  const float* W2    = (const float*)d_in[6];
  const float* b2    = (const float*)d_in[7];
  float* out = (float*)d_out;

  int n = in_sizes[0] / 64;
  int e = in_sizes[1] / 2;
  const int* srcv = ei;
  const int* dstv = ei + e;

  char* ws = (char*)d_ws;
  size_t p = 0;
  auto alloc = [&](size_t bytes) {
    void* r = ws + p;
    p += (bytes + 255) & ~(size_t)255;
    return r;
  };
  int*    counts = (int*)alloc((size_t)n * 4);
  int*    off    = (int*)alloc((size_t)(n + 1) * 4);
  int*    bsums  = (int*)alloc(1024);
  float*  dinv   = (float*)alloc((size_t)(n + 1) * 4);
  int*    csr    = (int*)alloc((size_t)(e + 3 * n + 64) * 4);  // padded segs + prefetch tail
  double* st     = (double*)alloc(128 * 8);
  float*  A      = (float*)alloc((size_t)(n + 1) * 64 * 4);    // gemm out (+ zero sentinel row)
  float*  B      = (float*)alloc((size_t)n * 64 * 4);          // agg1 out

  hipMemsetAsync(counts, 0, (size_t)n * 4, stream);
  hipMemsetAsync(st, 0, 128 * 8, stream);
  hipMemsetAsync(A + (size_t)n * 64, 0, 256, stream);  // sentinel row = zeros

  int gE = (e + 255) / 256;
  int gN = (n + 255) / 256;
  int nb = n / 1024 + 1;
  int gG = (n + 63) / 64;
  int gAgg = (n + 3) / 4;

  k_count<<<gE, 256, 0, stream>>>(dstv, counts, e);
  k_scanA<<<nb, 256, 0, stream>>>(counts, off, bsums, dinv, n);
  k_scanB<<<1, 256, 0, stream>>>(bsums, nb);
  k_padfill<<<gN, 256, 0, stream>>>(counts, off, bsums, csr, dinv, n);
  k_scatter<<<gE, 256, 0, stream>>>(srcv, dstv, off, bsums, counts, csr, e);

  k_gemm<false><<<gG, 256, 0, stream>>>(x, W1, A, n, nullptr, nullptr, nullptr);
  k_agg<true><<<gAgg, 256, 0, stream>>>(A, B, off, bsums, csr, dinv, b1, st, n);
  k_gemm<true><<<gG, 256, 0, stream>>>(B, W2, A, n, st, gamma, beta);
  k_agg<false><<<gAgg, 256, 0, stream>>>(A, out, off, bsums, csr, dinv, b2, nullptr, n);
}

// Round 5
// 400.794 us; speedup vs baseline: 2.2268x; 2.1185x over previous
//
#include <hip/hip_runtime.h>

#define LEAKY 0.01f
#define BN_EPS 1e-5f

// ---------------- degree count ----------------
__global__ __launch_bounds__(256) void k_count(const int* __restrict__ dst,
                                               int* __restrict__ cnt, int e) {
  int i = blockIdx.x * 256 + threadIdx.x;
  if (i < e) atomicAdd(&cnt[dst[i]], 1);
}

// ---------------- scanA: dinv + local exclusive scan of PADDED counts ----------------
__global__ __launch_bounds__(256) void k_scanA(const int* __restrict__ cnt,
                                               int* __restrict__ out,
                                               int* __restrict__ bsums,
                                               float* __restrict__ dinv, int n) {
  __shared__ int sdata[256];
  int t = threadIdx.x;
  int base = blockIdx.x * 1024 + t * 4;
  int pv[4];
#pragma unroll
  for (int j = 0; j < 4; j++) {
    int c = (base + j < n) ? cnt[base + j] : 0;
    if (base + j < n) dinv[base + j] = rsqrtf((float)(c + 1));  // +1 self-loop
    pv[j] = (base + j < n) ? ((c + 3) & ~3) : 0;
  }
  int tsum = pv[0] + pv[1] + pv[2] + pv[3];
  sdata[t] = tsum;
  __syncthreads();
  for (int off = 1; off < 256; off <<= 1) {
    int x = (t >= off) ? sdata[t - off] : 0;
    __syncthreads();
    sdata[t] += x;
    __syncthreads();
  }
  int run = sdata[t] - tsum;
#pragma unroll
  for (int j = 0; j < 4; j++) {
    if (base + j < n) out[base + j] = run;
    else if (base + j == n) out[n] = run;  // one-past-end slot
    run += pv[j];
  }
  if (t == 255) bsums[blockIdx.x] = sdata[255];
}

__global__ __launch_bounds__(256) void k_scanB(int* __restrict__ bsums, int nb) {
  __shared__ int sdata[256];
  int t = threadIdx.x;
  int v = (t < nb) ? bsums[t] : 0;
  sdata[t] = v;
  __syncthreads();
  for (int off = 1; off < 256; off <<= 1) {
    int x = (t >= off) ? sdata[t - off] : 0;
    __syncthreads();
    sdata[t] += x;
    __syncthreads();
  }
  if (t < nb) bsums[t] = sdata[t] - v;  // exclusive
}

// ---------------- fill pad slots with sentinel n ----------------
__global__ __launch_bounds__(256) void k_padfill(const int* __restrict__ cnt,
                                                 const int* __restrict__ off,
                                                 const int* __restrict__ bsums,
                                                 int* __restrict__ csr, int n) {
  int i = blockIdx.x * 256 + threadIdx.x;
  if (i < n) {
    int c = cnt[i];
    int pc = (c + 3) & ~3;
    int base = off[i] + bsums[i >> 10];
    for (int j = c; j < pc; j++) csr[base + j] = n;  // sentinel -> zero row
  }
}

// ---------------- CSR scatter (consumes counts down to 0) ----------------
__global__ __launch_bounds__(256) void k_scatter(const int* __restrict__ src,
                                                 const int* __restrict__ dst,
                                                 const int* __restrict__ off,
                                                 const int* __restrict__ bsums,
                                                 int* __restrict__ cnt,
                                                 int* __restrict__ csr, int e) {
  int i = blockIdx.x * 256 + threadIdx.x;
  if (i < e) {
    int d = dst[i];
    int p = off[d] + bsums[d >> 10] + (atomicSub(&cnt[d], 1) - 1);
    csr[p] = src[i];
  }
}

// ---------------- 64x64 GEMM: Y[r] = (X[r] @ W) * dinv[r] ; BN+LeakyReLU fused on X
template <bool BN>
__global__ __launch_bounds__(256) void k_gemm(const float* __restrict__ X,
                                              const float* __restrict__ W,
                                              float* __restrict__ Y, int n,
                                              const float* __restrict__ dinv,
                                              const double* __restrict__ st,
                                              const float* __restrict__ gamma,
                                              const float* __restrict__ beta) {
  __shared__ float Ws[64][68];
  __shared__ float Xs[64][68];
  __shared__ float smu[64], sisd[64];
  int t = threadIdx.x;
  if (BN) {
    if (t < 64) {
      double mu = st[t] / n;
      double var = st[64 + t] / n - mu * mu;
      smu[t] = (float)mu;
      sisd[t] = (float)(1.0 / sqrt(var + (double)BN_EPS));
    }
    __syncthreads();
  }
  int rowbase = blockIdx.x * 64;
#pragma unroll
  for (int p = 0; p < 4; p++) {
    int idx = (p * 256 + t) * 4;
    int r = idx >> 6, c = idx & 63;
    float4 wv = *(const float4*)&W[idx];
    *(float4*)&Ws[r][c] = wv;
    int gr = rowbase + r;
    float4 v = (gr < n) ? *(const float4*)&X[(size_t)gr * 64 + c]
                        : make_float4(0.f, 0.f, 0.f, 0.f);
    if (BN) {
      float* vp = (float*)&v;
#pragma unroll
      for (int q = 0; q < 4; q++) {
        float z = gamma[c + q] * (vp[q] - smu[c + q]) * sisd[c + q] + beta[c + q];
        vp[q] = (z >= 0.f) ? z : LEAKY * z;
      }
    }
    *(float4*)&Xs[r][c] = v;
  }
  __syncthreads();
  int r = t >> 2;
  int cq = t & 3;
  float acc[16];
#pragma unroll
  for (int j = 0; j < 16; j++) acc[j] = 0.f;
#pragma unroll 4
  for (int k = 0; k < 64; k++) {
    float xv = Xs[r][k];
#pragma unroll
    for (int j = 0; j < 16; j++) acc[j] += xv * Ws[k][cq * 16 + j];
  }
  int gr = rowbase + r;
  if (gr < n) {
    float dv = dinv[gr];  // pre-scale: gathered tensor is h*dinv
#pragma unroll
    for (int j = 0; j < 16; j++) acc[j] *= dv;
#pragma unroll
    for (int q = 0; q < 4; q++)
      *(float4*)&Y[(size_t)gr * 64 + cq * 16 + q * 4] = *(float4*)&acc[q * 4];
  }
}

// ---------------- gather aggregation: O[i] = dinv_i * (sum A'[src] + A'[i]) + b
// A' rows pre-scaled by dinv; segments padded x4 with sentinel n (zero row).
// No LDS, no barrier, no template. 4-deep named scalars, int4 csr + prefetch.
__global__ __launch_bounds__(256) void k_agg(const float* __restrict__ H,
                                             float* __restrict__ O,
                                             const int* __restrict__ off,
                                             const int* __restrict__ bsums,
                                             const int* __restrict__ csr,
                                             const float* __restrict__ dinv,
                                             const float* __restrict__ bias, int n) {
  int wave = (blockIdx.x * 256 + threadIdx.x) >> 6;
  int lane = threadIdx.x & 63;
  int i = wave;
  if (i >= n) return;
  float di = dinv[i];
  int s0 = off[i] + bsums[i >> 10];
  int s1 = off[i + 1] + bsums[(i + 1) >> 10];
  float acc = H[(size_t)i * 64 + lane];  // self-loop (already *dinv_i)
  const int4* cp = (const int4*)csr;
  int j = s0 >> 2, jend = s1 >> 2;
  int4 q = cp[j];
  for (; j < jend; ++j) {
    int4 qn = cp[j + 1];  // prefetch next chunk (alloc has tail pad)
    float h0 = H[(size_t)q.x * 64 + lane];
    float h1 = H[(size_t)q.y * 64 + lane];
    float h2 = H[(size_t)q.z * 64 + lane];
    float h3 = H[(size_t)q.w * 64 + lane];
    acc += h0;
    acc += h1;
    acc += h2;
    acc += h3;
    q = qn;
  }
  O[(size_t)i * 64 + lane] = di * acc + bias[lane];
}

// ---------------- BN batch stats (separate, 256 blocks -> 32K atomics) ----------------
__global__ __launch_bounds__(256) void k_bnstats(const float* __restrict__ H,
                                                 double* __restrict__ st, int n) {
  __shared__ double ls[4][64], lss[4][64];
  int lane = threadIdx.x & 63;
  int w = threadIdx.x >> 6;
  int rw = blockIdx.x * 4 + w;
  int nrw = gridDim.x * 4;
  double s = 0.0, ss = 0.0;
  for (int r = rw; r < n; r += nrw) {
    float v = H[(size_t)r * 64 + lane];
    s += v;
    ss += (double)v * v;
  }
  ls[w][lane] = s;
  lss[w][lane] = ss;
  __syncthreads();
  if (w == 0) {
    double a = ls[0][lane] + ls[1][lane] + ls[2][lane] + ls[3][lane];
    double b = lss[0][lane] + lss[1][lane] + lss[2][lane] + lss[3][lane];
    atomicAdd(&st[lane], a);
    atomicAdd(&st[64 + lane], b);
  }
}

extern "C" void kernel_launch(void* const* d_in, const int* in_sizes, int n_in,
                              void* d_out, int out_size, void* d_ws, size_t ws_size,
                              hipStream_t stream) {
  const float* x     = (const float*)d_in[0];
  const int*   ei    = (const int*)d_in[1];
  const float* W1    = (const float*)d_in[2];
  const float* b1    = (const float*)d_in[3];
  const float* gamma = (const float*)d_in[4];
  const float* beta  = (const float*)d_in[5];
  const float* W2    = (const float*)d_in[6];
  const float* b2    = (const float*)d_in[7];
  float* out = (float*)d_out;

  int n = in_sizes[0] / 64;
  int e = in_sizes[1] / 2;
  const int* srcv = ei;
  const int* dstv = ei + e;

  char* ws = (char*)d_ws;
  size_t p = 0;
  auto alloc = [&](size_t bytes) {
    void* r = ws + p;
    p += (bytes + 255) & ~(size_t)255;
    return r;
  };
  int*    counts = (int*)alloc((size_t)n * 4);
  int*    off    = (int*)alloc((size_t)(n + 1) * 4);
  int*    bsums  = (int*)alloc(1024);
  float*  dinv   = (float*)alloc((size_t)(n + 1) * 4);
  int*    csr    = (int*)alloc((size_t)(e + 3 * n + 64) * 4);  // padded segs + prefetch tail
  double* st     = (double*)alloc(128 * 8);
  float*  A      = (float*)alloc((size_t)(n + 1) * 64 * 4);    // gemm out *dinv (+ zero row n)
  float*  B      = (float*)alloc((size_t)n * 64 * 4);          // agg1 out

  hipMemsetAsync(counts, 0, (size_t)n * 4, stream);
  hipMemsetAsync(st, 0, 128 * 8, stream);
  hipMemsetAsync(A + (size_t)n * 64, 0, 256, stream);  // sentinel row = zeros

  int gE = (e + 255) / 256;
  int gN = (n + 255) / 256;
  int nb = n / 1024 + 1;
  int gG = (n + 63) / 64;
  int gAgg = (n + 3) / 4;

  k_count<<<gE, 256, 0, stream>>>(dstv, counts, e);
  k_scanA<<<nb, 256, 0, stream>>>(counts, off, bsums, dinv, n);
  k_scanB<<<1, 256, 0, stream>>>(bsums, nb);
  k_padfill<<<gN, 256, 0, stream>>>(counts, off, bsums, csr, n);
  k_scatter<<<gE, 256, 0, stream>>>(srcv, dstv, off, bsums, counts, csr, e);

  k_gemm<false><<<gG, 256, 0, stream>>>(x, W1, A, n, dinv, nullptr, nullptr, nullptr);
  k_agg<<<gAgg, 256, 0, stream>>>(A, B, off, bsums, csr, dinv, b1, n);
  k_bnstats<<<256, 256, 0, stream>>>(B, st, n);
  k_gemm<true><<<gG, 256, 0, stream>>>(B, W2, A, n, dinv, st, gamma, beta);
  k_agg<<<gAgg, 256, 0, stream>>>(A, out, off, bsums, csr, dinv, b2, n);
}

// Round 6
// 321.196 us; speedup vs baseline: 2.7786x; 1.2478x over previous
//
#include <hip/hip_runtime.h>
#include <hip/hip_fp16.h>

#define LEAKY 0.01f
#define BN_EPS 1e-5f

// ---------------- degree count ----------------
__global__ __launch_bounds__(256) void k_count(const int* __restrict__ dst,
                                               int* __restrict__ cnt, int e) {
  int i = blockIdx.x * 256 + threadIdx.x;
  if (i < e) atomicAdd(&cnt[dst[i]], 1);
}

// ---------------- scanA: dinv + local exclusive scan of counts padded to x8 ----------------
__global__ __launch_bounds__(256) void k_scanA(const int* __restrict__ cnt,
                                               int* __restrict__ out,
                                               int* __restrict__ bsums,
                                               float* __restrict__ dinv, int n) {
  __shared__ int sdata[256];
  int t = threadIdx.x;
  int base = blockIdx.x * 1024 + t * 4;
  int pv[4];
#pragma unroll
  for (int j = 0; j < 4; j++) {
    int c = (base + j < n) ? cnt[base + j] : 0;
    if (base + j < n) dinv[base + j] = rsqrtf((float)(c + 1));  // +1 self-loop
    pv[j] = (base + j < n) ? ((c + 7) & ~7) : 0;                // pad to x8
  }
  int tsum = pv[0] + pv[1] + pv[2] + pv[3];
  sdata[t] = tsum;
  __syncthreads();
  for (int off = 1; off < 256; off <<= 1) {
    int x = (t >= off) ? sdata[t - off] : 0;
    __syncthreads();
    sdata[t] += x;
    __syncthreads();
  }
  int run = sdata[t] - tsum;
#pragma unroll
  for (int j = 0; j < 4; j++) {
    if (base + j < n) out[base + j] = run;
    else if (base + j == n) out[n] = run;  // one-past-end slot
    run += pv[j];
  }
  if (t == 255) bsums[blockIdx.x] = sdata[255];
}

__global__ __launch_bounds__(256) void k_scanB(int* __restrict__ bsums, int nb) {
  __shared__ int sdata[256];
  int t = threadIdx.x;
  int v = (t < nb) ? bsums[t] : 0;
  sdata[t] = v;
  __syncthreads();
  for (int off = 1; off < 256; off <<= 1) {
    int x = (t >= off) ? sdata[t - off] : 0;
    __syncthreads();
    sdata[t] += x;
    __syncthreads();
  }
  if (t < nb) bsums[t] = sdata[t] - v;  // exclusive
}

// ---------------- pad-fill, XCD-local (blockIdx&7 -> node range) ----------------
__global__ __launch_bounds__(256) void k_padfill(const int* __restrict__ cnt,
                                                 const int* __restrict__ off,
                                                 const int* __restrict__ bsums,
                                                 int* __restrict__ csr, int n) {
  int k = blockIdx.x & 7;
  int g = blockIdx.x >> 3;
  int nper = (n + 7) >> 3;
  int lo = k * nper;
  int hi = min(n, lo + nper);
  int i = lo + g * 256 + threadIdx.x;
  if (i < hi) {
    int c = cnt[i];
    int pc = (c + 7) & ~7;
    int base = off[i] + bsums[i >> 10];
    for (int j = c; j < pc; j++) csr[base + j] = n;  // sentinel -> zero row
  }
}

// ---------------- CSR scatter, XCD-local: block handles only its node range ----------------
__global__ __launch_bounds__(256) void k_scatter(const int* __restrict__ src,
                                                 const int* __restrict__ dst,
                                                 const int* __restrict__ off,
                                                 const int* __restrict__ bsums,
                                                 int* __restrict__ cnt,
                                                 int* __restrict__ csr, int e, int n) {
  int k = blockIdx.x & 7;
  int g = blockIdx.x >> 3;
  int ngroups = gridDim.x >> 3;
  int nper = (n + 7) >> 3;
  int lo = k * nper;
  int hi = min(n, lo + nper);
  for (int i = g * 256 + threadIdx.x; i < e; i += ngroups * 256) {
    int d = dst[i];
    if (d >= lo && d < hi) {
      int p = off[d] + bsums[d >> 10] + (atomicSub(&cnt[d], 1) - 1);
      csr[p] = src[i];
    }
  }
}

// ---------------- 64x64 GEMM: Y[r](fp16) = (X[r] @ W) * dinv[r] ; BN+LeakyReLU fused on X
template <bool BN>
__global__ __launch_bounds__(256) void k_gemm(const float* __restrict__ X,
                                              const float* __restrict__ W,
                                              __half* __restrict__ Y, int n,
                                              const float* __restrict__ dinv,
                                              const double* __restrict__ st,
                                              const float* __restrict__ gamma,
                                              const float* __restrict__ beta) {
  __shared__ float Ws[64][68];
  __shared__ float Xs[64][68];
  __shared__ float smu[64], sisd[64];
  int t = threadIdx.x;
  if (BN) {
    if (t < 64) {
      double mu = st[t] / n;
      double var = st[64 + t] / n - mu * mu;
      smu[t] = (float)mu;
      sisd[t] = (float)(1.0 / sqrt(var + (double)BN_EPS));
    }
    __syncthreads();
  }
  int rowbase = blockIdx.x * 64;
#pragma unroll
  for (int p = 0; p < 4; p++) {
    int idx = (p * 256 + t) * 4;
    int r = idx >> 6, c = idx & 63;
    float4 wv = *(const float4*)&W[idx];
    *(float4*)&Ws[r][c] = wv;
    int gr = rowbase + r;
    float4 v = (gr < n) ? *(const float4*)&X[(size_t)gr * 64 + c]
                        : make_float4(0.f, 0.f, 0.f, 0.f);
    if (BN) {
      float* vp = (float*)&v;
#pragma unroll
      for (int q = 0; q < 4; q++) {
        float z = gamma[c + q] * (vp[q] - smu[c + q]) * sisd[c + q] + beta[c + q];
        vp[q] = (z >= 0.f) ? z : LEAKY * z;
      }
    }
    *(float4*)&Xs[r][c] = v;
  }
  __syncthreads();
  int r = t >> 2;
  int cq = t & 3;
  float acc[16];
#pragma unroll
  for (int j = 0; j < 16; j++) acc[j] = 0.f;
#pragma unroll 4
  for (int k = 0; k < 64; k++) {
    float xv = Xs[r][k];
#pragma unroll
    for (int j = 0; j < 16; j++) acc[j] += xv * Ws[k][cq * 16 + j];
  }
  int gr = rowbase + r;
  if (gr < n) {
    float dv = dinv[gr];  // pre-scale: gathered tensor is h*dinv
    __half2 h2[8];
#pragma unroll
    for (int j = 0; j < 8; j++)
      h2[j] = __floats2half2_rn(acc[2 * j] * dv, acc[2 * j + 1] * dv);
    __half* yp = &Y[(size_t)gr * 64 + cq * 16];
    *(int4*)yp = *(int4*)&h2[0];
    *(int4*)(yp + 8) = *(int4*)&h2[4];
  }
}

// ---------------- gather aggregation, fp16 rows, dual-edge half-waves ----------------
// O[i] = dinv_i * (sum_src A'[src] + A'[i]) + b ; A' pre-scaled by dinv, row n = zeros.
// Lanes 0-31 gather even edge slots, 32-63 odd; each lane loads __half2 (cols 2m,2m+1).
// 8 edges per iteration (segments padded to x8) -> 4 outstanding gathers per lane.
__global__ __launch_bounds__(256) void k_agg(const __half* __restrict__ H,
                                             float* __restrict__ O,
                                             const int* __restrict__ off,
                                             const int* __restrict__ bsums,
                                             const int* __restrict__ csr,
                                             const float* __restrict__ dinv,
                                             const float* __restrict__ bias, int n) {
  int wave = (blockIdx.x * 256 + threadIdx.x) >> 6;
  int lane = threadIdx.x & 63;
  int i = wave;
  if (i >= n) return;
  float di = dinv[i];
  int s0 = off[i] + bsums[i >> 10];
  int s1 = off[i + 1] + bsums[(i + 1) >> 10];
  int m = lane & 31;
  bool loA = lane < 32;
  // self contribution (count once: only lower half accumulates it)
  float2 sf = __half22float2(*(const __half2*)&H[(size_t)i * 64 + 2 * m]);
  float a0 = loA ? sf.x : 0.f;
  float a1 = loA ? sf.y : 0.f;
  const int4* cp = (const int4*)csr;
  int j = s0 >> 2, jend = s1 >> 2;
  int4 q0 = cp[j];
  int4 q1 = cp[j + 1];
  for (; j < jend; j += 2) {
    int4 p0 = cp[j + 2];  // prefetch (tail pad covers over-read)
    int4 p1 = cp[j + 3];
    int i0 = loA ? q0.x : q0.y;
    int i1 = loA ? q0.z : q0.w;
    int i2 = loA ? q1.x : q1.y;
    int i3 = loA ? q1.z : q1.w;
    float2 f0 = __half22float2(*(const __half2*)&H[(size_t)i0 * 64 + 2 * m]);
    float2 f1 = __half22float2(*(const __half2*)&H[(size_t)i1 * 64 + 2 * m]);
    float2 f2 = __half22float2(*(const __half2*)&H[(size_t)i2 * 64 + 2 * m]);
    float2 f3 = __half22float2(*(const __half2*)&H[(size_t)i3 * 64 + 2 * m]);
    a0 += f0.x + f1.x + f2.x + f3.x;
    a1 += f0.y + f1.y + f2.y + f3.y;
    q0 = p0;
    q1 = p1;
  }
  a0 += __shfl_xor(a0, 32, 64);
  a1 += __shfl_xor(a1, 32, 64);
  if (loA) {
    float2 bv = *(const float2*)&bias[2 * m];
    float2 o;
    o.x = di * a0 + bv.x;
    o.y = di * a1 + bv.y;
    *(float2*)&O[(size_t)i * 64 + 2 * m] = o;
  }
}

// ---------------- BN batch stats (256 blocks -> 32K atomics) ----------------
__global__ __launch_bounds__(256) void k_bnstats(const float* __restrict__ H,
                                                 double* __restrict__ st, int n) {
  __shared__ double ls[4][64], lss[4][64];
  int lane = threadIdx.x & 63;
  int w = threadIdx.x >> 6;
  int rw = blockIdx.x * 4 + w;
  int nrw = gridDim.x * 4;
  double s = 0.0, ss = 0.0;
  for (int r = rw; r < n; r += nrw) {
    float v = H[(size_t)r * 64 + lane];
    s += v;
    ss += (double)v * v;
  }
  ls[w][lane] = s;
  lss[w][lane] = ss;
  __syncthreads();
  if (w == 0) {
    double a = ls[0][lane] + ls[1][lane] + ls[2][lane] + ls[3][lane];
    double b = lss[0][lane] + lss[1][lane] + lss[2][lane] + lss[3][lane];
    atomicAdd(&st[lane], a);
    atomicAdd(&st[64 + lane], b);
  }
}

extern "C" void kernel_launch(void* const* d_in, const int* in_sizes, int n_in,
                              void* d_out, int out_size, void* d_ws, size_t ws_size,
                              hipStream_t stream) {
  const float* x     = (const float*)d_in[0];
  const int*   ei    = (const int*)d_in[1];
  const float* W1    = (const float*)d_in[2];
  const float* b1    = (const float*)d_in[3];
  const float* gamma = (const float*)d_in[4];
  const float* beta  = (const float*)d_in[5];
  const float* W2    = (const float*)d_in[6];
  const float* b2    = (const float*)d_in[7];
  float* out = (float*)d_out;

  int n = in_sizes[0] / 64;
  int e = in_sizes[1] / 2;
  const int* srcv = ei;
  const int* dstv = ei + e;

  char* ws = (char*)d_ws;
  size_t p = 0;
  auto alloc = [&](size_t bytes) {
    void* r = ws + p;
    p += (bytes + 255) & ~(size_t)255;
    return r;
  };
  int*    counts = (int*)alloc((size_t)n * 4);
  int*    off    = (int*)alloc((size_t)(n + 1) * 4);
  int*    bsums  = (int*)alloc(1024);
  float*  dinv   = (float*)alloc((size_t)(n + 1) * 4);
  int*    csr    = (int*)alloc((size_t)(e + 7 * n + 128) * 4);  // x8-padded segs + prefetch tail
  double* st     = (double*)alloc(128 * 8);
  __half* A      = (__half*)alloc((size_t)(n + 1) * 64 * 2);    // gemm out *dinv, fp16 (+ zero row n)
  float*  B      = (float*)alloc((size_t)n * 64 * 4);           // agg1 out, fp32

  hipMemsetAsync(counts, 0, (size_t)n * 4, stream);
  hipMemsetAsync(st, 0, 128 * 8, stream);
  hipMemsetAsync(A + (size_t)n * 64, 0, 128, stream);  // sentinel row = zeros

  int gE = (e + 255) / 256;
  int nb = n / 1024 + 1;
  int gG = (n + 63) / 64;
  int gAgg = (n + 3) / 4;
  int nper = (n + 7) / 8;
  int gPad = 8 * ((nper + 255) / 256);
  int gScat = 8 * 128;

  k_count<<<gE, 256, 0, stream>>>(dstv, counts, e);
  k_scanA<<<nb, 256, 0, stream>>>(counts, off, bsums, dinv, n);
  k_scanB<<<1, 256, 0, stream>>>(bsums, nb);
  k_padfill<<<gPad, 256, 0, stream>>>(counts, off, bsums, csr, n);
  k_scatter<<<gScat, 256, 0, stream>>>(srcv, dstv, off, bsums, counts, csr, e, n);

  k_gemm<false><<<gG, 256, 0, stream>>>(x, W1, A, n, dinv, nullptr, nullptr, nullptr);
  k_agg<<<gAgg, 256, 0, stream>>>(A, B, off, bsums, csr, dinv, b1, n);
  k_bnstats<<<256, 256, 0, stream>>>(B, st, n);
  k_gemm<true><<<gG, 256, 0, stream>>>(B, W2, A, n, dinv, st, gamma, beta);
  k_agg<<<gAgg, 256, 0, stream>>>(A, out, off, bsums, csr, dinv, b2, n);
}